// Round 7
// baseline (221.209 us; speedup 1.0000x reference)
//
#include <hip/hip_runtime.h>
#include <math.h>

#define L_ 4096
#define B_ 4
#define D_ 512
#define V_ 1000
#define VP 1024
#define BD 2048     // B_*D_
#define OUT_BV 4000 // B_*V_
#define NCH 16      // split-K chunks for kGbf (640 blocks after symmetry cut)

typedef __attribute__((ext_vector_type(8))) short short8;
typedef __attribute__((ext_vector_type(4))) float f32x4;
typedef __attribute__((ext_vector_type(4))) short short4v;

typedef __attribute__((address_space(1))) const unsigned int gu32;
typedef __attribute__((address_space(3))) unsigned int lu32;

// async global->LDS DMA, 16 B/lane (wave-level: lands at ldsbase + lane*16)
__device__ __forceinline__ void dma16(const void* g, void* l) {
  __builtin_amdgcn_global_load_lds((gu32*)g, (lu32*)l, 16, 0, 0);
}

__device__ __forceinline__ short f2bf(float f) {
  unsigned u = __float_as_uint(f);
  unsigned r = (u + 0x7FFFu + ((u >> 16) & 1u)) >> 16;
  return (short)r;
}
__device__ __forceinline__ float bf2f(short v) {
  return __uint_as_float(((unsigned)(unsigned short)v) << 16);
}

// ---------------------------------------------------------------------------
// kPre: one pass over x. Produces (ALL bf16 outputs PRE-SWIZZLED: within each
// 64-elem row-chunk, 8-elem block blk is stored at blk ^ (row&7) — so that a
// linear global_load_lds DMA lands in the XOR-swizzled LDS layout):
//   xbf (B,L,D); xT (B,D,L); s[b,d]=sum_l x (atomic); c[b,l]=x·Wb (atomic)
// ---------------------------------------------------------------------------
__global__ __launch_bounds__(256) void kPre(const float* __restrict__ x,
                                            const float* __restrict__ Wb,
                                            short* __restrict__ xbf,
                                            short* __restrict__ xT,
                                            float* __restrict__ s,
                                            float* __restrict__ c) {
  const int l0 = blockIdx.x * 64, d0 = blockIdx.y * 64, b = blockIdx.z;
  __shared__ short tile[64 * 72];  // tile[d_local][l_local], stride 72
  const int tid = threadIdx.x;
  const int r = tid >> 2;
  const int q = tid & 3;
  const int c0 = q * 16;
  const int key = r & 7;
  const int blk0 = c0 >> 3;  // 0,2,4,6

  short sv[16];
  float cpart = 0.f;
  const float* src = x + (size_t)(l0 + r) * BD + b * D_ + d0 + c0;
#pragma unroll
  for (int qq = 0; qq < 4; ++qq) {
    float4 f = *(const float4*)(src + qq * 4);
    const float* wb = Wb + d0 + c0 + qq * 4;
    cpart += f.x * wb[0] + f.y * wb[1] + f.z * wb[2] + f.w * wb[3];
    sv[qq * 4 + 0] = f2bf(f.x); sv[qq * 4 + 1] = f2bf(f.y);
    sv[qq * 4 + 2] = f2bf(f.z); sv[qq * 4 + 3] = f2bf(f.w);
  }
  // swizzled xbf store (row = l0+r, chunk base d0)
  short* dst = xbf + ((size_t)b * L_ + l0 + r) * D_ + d0;
  *(short8*)(dst + ((blk0 ^ key) * 8))       = *(short8*)(sv);
  *(short8*)(dst + (((blk0 + 1) ^ key) * 8)) = *(short8*)(sv + 8);
#pragma unroll
  for (int i = 0; i < 16; ++i) tile[(c0 + i) * 72 + r] = sv[i];
  cpart += __shfl_xor(cpart, 1);
  cpart += __shfl_xor(cpart, 2);
  if (q == 0) atomicAdd(&c[b * L_ + l0 + r], cpart);
  __syncthreads();
  short8 t0 = *(const short8*)(tile + r * 72 + c0);
  short8 t1 = *(const short8*)(tile + r * 72 + c0 + 8);
  // swizzled xT store (row = d0+r, chunk base l0)
  short* tdst = xT + ((size_t)b * D_ + d0 + r) * L_ + l0;
  *(short8*)(tdst + ((blk0 ^ key) * 8))       = t0;
  *(short8*)(tdst + (((blk0 + 1) ^ key) * 8)) = t1;
  float spart = 0.f;
#pragma unroll
  for (int i = 0; i < 8; ++i) spart += bf2f(t0[i]) + bf2f(t1[i]);
  spart += __shfl_xor(spart, 1);
  spart += __shfl_xor(spart, 2);
  if (q == 0) atomicAdd(&s[b * D_ + d0 + r], spart);
}

// ---------------------------------------------------------------------------
// kGbf: Gpart[z] = xT_b[:,chunk] . xT_b[:,chunk]^T — SYMMETRIC: only the 10
// upper-triangular 128x128 tile pairs; off-diagonal tiles mirror-write.
// Staging via global_load_lds from pre-swizzled xT.
// ---------------------------------------------------------------------------
__global__ __launch_bounds__(256) void kGbf(const short* __restrict__ xT,
                                            short* __restrict__ Gpart) {
  const int z = blockIdx.z;
  const int b = z >> 4, ch = z & 15;
  const int p = blockIdx.x;
  int ti, tj;
  if (p < 4)      { ti = 0; tj = p; }
  else if (p < 7) { ti = 1; tj = p - 3; }
  else if (p < 9) { ti = 2; tj = p - 5; }
  else            { ti = 3; tj = 3; }
  const int i0 = ti * 128, j0 = tj * 128;
  const bool mirror = (ti != tj);
  const short* Ab = xT + (size_t)b * D_ * L_;
  __shared__ short As[128 * 64];
  __shared__ short Bs[128 * 64];
  f32x4 acc[4][4] = {};
  const int tid = threadIdx.x;
  const int w = tid >> 6, lane = tid & 63;
  const int quad = lane >> 4, mcol = lane & 15;
  const int wr0 = (w & 1) * 64, wc0 = (w >> 1) * 64;
  const int kbase = ch * (L_ / NCH);

  for (int k0 = kbase; k0 < kbase + (L_ / NCH); k0 += 64) {
#pragma unroll
    for (int t = 0; t < 4; ++t) {
      const int cc = w * 4 + t;               // chunk: 8 rows of the tile
      const int gr = cc * 8 + (lane >> 3);
      const int gc = k0 + (lane & 7) * 8;
      dma16(Ab + (size_t)(i0 + gr) * L_ + gc, As + cc * 512);
      dma16(Ab + (size_t)(j0 + gr) * L_ + gc, Bs + cc * 512);
    }
    __syncthreads();
#pragma unroll
    for (int ss = 0; ss < 2; ++ss) {
      short8 af[4], bf[4];
#pragma unroll
      for (int i = 0; i < 4; ++i) {
        const int arow = wr0 + i * 16 + mcol;
        const int ablk = (ss * 4 + quad) ^ (arow & 7);
        af[i] = *(const short8*)(As + arow * 64 + ablk * 8);
        const int brow = wc0 + i * 16 + mcol;
        const int bblk = (ss * 4 + quad) ^ (brow & 7);
        bf[i] = *(const short8*)(Bs + brow * 64 + bblk * 8);
      }
#pragma unroll
      for (int i = 0; i < 4; ++i)
#pragma unroll
        for (int j = 0; j < 4; ++j)
          acc[i][j] = __builtin_amdgcn_mfma_f32_16x16x32_bf16(af[i], bf[j],
                                                              acc[i][j], 0, 0, 0);
    }
    __syncthreads();
  }
  short* Gp = Gpart + (size_t)z * (D_ * D_);
#pragma unroll
  for (int i = 0; i < 4; ++i)
#pragma unroll
    for (int j = 0; j < 4; ++j) {
      const int col = j0 + wc0 + j * 16 + mcol;
#pragma unroll
      for (int r = 0; r < 4; ++r) {
        const int rowi = i0 + wr0 + i * 16 + quad * 4 + r;
        const short v = f2bf(acc[i][j][r]);
        Gp[(size_t)rowi * D_ + col] = v;
        if (mirror) Gp[(size_t)col * D_ + rowi] = v;
      }
    }
}

// ---------------------------------------------------------------------------
// kGredWT: blocks [0,512): Gb = sum_ch Gpart.  [512,1280): cast Ww/Lw -> bf16.
// [1280,2304): t[b][v] = dot(Lw[v,:], s[b,:])  (merged kT).
// ---------------------------------------------------------------------------
__global__ __launch_bounds__(256) void kGredWT(const short* __restrict__ Gpart,
                                               short* __restrict__ Gb,
                                               const float* __restrict__ Ww,
                                               const float* __restrict__ Lw,
                                               short* __restrict__ Wwb,
                                               short* __restrict__ Lwb,
                                               const float* __restrict__ s,
                                               float* __restrict__ t) {
  if (blockIdx.x < 512) {
    const int idx = blockIdx.x * 256 + threadIdx.x;  // short8 index
    const int b = idx >> 15, e = (idx & 32767) * 8;
    float sum[8] = {};
#pragma unroll
    for (int ch = 0; ch < NCH; ++ch) {
      short8 v = *(const short8*)(Gpart + ((size_t)(b * NCH + ch)) * (D_ * D_) + e);
#pragma unroll
      for (int i = 0; i < 8; ++i) sum[i] += bf2f(v[i]);
    }
    short8 o;
#pragma unroll
    for (int i = 0; i < 8; ++i) o[i] = f2bf(sum[i]);
    *(short8*)(Gb + (size_t)b * (D_ * D_) + e) = o;
  } else if (blockIdx.x < 1280) {
    const int idx = (blockIdx.x - 512) * 256 + threadIdx.x;  // quad index
    if (idx < 65536) {
      const int e = idx * 4;
      float4 f = *(const float4*)(Ww + e);
      short4v o; o[0] = f2bf(f.x); o[1] = f2bf(f.y); o[2] = f2bf(f.z); o[3] = f2bf(f.w);
      *(short4v*)(Wwb + e) = o;
    } else {
      const int e = (idx - 65536) * 4;
      const int v = e >> 9;
      short4v o = {};
      if (v < V_) {
        float4 f = *(const float4*)(Lw + e);
        o[0] = f2bf(f.x); o[1] = f2bf(f.y); o[2] = f2bf(f.z); o[3] = f2bf(f.w);
      }
      *(short4v*)(Lwb + e) = o;
    }
  } else {
    const int w = threadIdx.x >> 6, lane = threadIdx.x & 63;
    const int wid = (blockIdx.x - 1280) * 4 + w;
    const int b = wid >> 10, v = wid & 1023;
    float sum = 0.f;
    if (v < V_) {
      const float* lr = Lw + (size_t)v * D_;
      const float* sb = s + b * D_;
#pragma unroll
      for (int i = 0; i < 8; ++i) sum += lr[lane + i * 64] * sb[lane + i * 64];
    }
    for (int off = 32; off; off >>= 1) sum += __shfl_down(sum, off);
    if (lane == 0) t[b * VP + v] = (v < V_) ? sum : 0.f;
  }
}

// ---------------------------------------------------------------------------
// kMbf64: Mb[b] = Wwb @ Gb[b]  (64x64 tiles; VGPR staging, unswizzled inputs)
// ---------------------------------------------------------------------------
__global__ __launch_bounds__(256) void kMbf64(const short* __restrict__ Wwb,
                                              const short* __restrict__ Gb,
                                              short* __restrict__ Mb) {
  const int b = blockIdx.z;
  const int i0 = blockIdx.x * 64, j0 = blockIdx.y * 64;
  const short* Bbase = Gb + (size_t)b * D_ * D_;
  __shared__ short As[64 * 64];
  __shared__ short Bs[64 * 64];
  f32x4 acc[2][2] = {};
  const int tid = threadIdx.x;
  const int w = tid >> 6, lane = tid & 63;
  const int quad = lane >> 4, mcol = lane & 15;
  const int wr0 = (w & 1) * 32, wc0 = (w >> 1) * 32;

  for (int k0 = 0; k0 < D_; k0 += 64) {
#pragma unroll
    for (int q = 0; q < 2; ++q) {
      const int u = q * 256 + tid;
      const int row = u >> 3, blk = u & 7;
      const int phys = blk ^ (row & 7);
      *(short8*)(As + row * 64 + phys * 8) =
          *(const short8*)(Wwb + (size_t)(i0 + row) * D_ + k0 + blk * 8);
      *(short8*)(Bs + row * 64 + phys * 8) =
          *(const short8*)(Bbase + (size_t)(j0 + row) * D_ + k0 + blk * 8);
    }
    __syncthreads();
#pragma unroll
    for (int ss = 0; ss < 2; ++ss) {
      short8 af[2], bf[2];
#pragma unroll
      for (int i = 0; i < 2; ++i) {
        const int arow = wr0 + i * 16 + mcol;
        const int ablk = (ss * 4 + quad) ^ (arow & 7);
        af[i] = *(const short8*)(As + arow * 64 + ablk * 8);
        const int brow = wc0 + i * 16 + mcol;
        const int bblk = (ss * 4 + quad) ^ (brow & 7);
        bf[i] = *(const short8*)(Bs + brow * 64 + bblk * 8);
      }
#pragma unroll
      for (int i = 0; i < 2; ++i)
#pragma unroll
        for (int j = 0; j < 2; ++j)
          acc[i][j] = __builtin_amdgcn_mfma_f32_16x16x32_bf16(af[i], bf[j],
                                                              acc[i][j], 0, 0, 0);
    }
    __syncthreads();
  }
  short* Mo = Mb + (size_t)b * D_ * D_;
#pragma unroll
  for (int i = 0; i < 2; ++i)
#pragma unroll
    for (int j = 0; j < 2; ++j) {
      const int col = j0 + wc0 + j * 16 + mcol;
#pragma unroll
      for (int r = 0; r < 4; ++r) {
        const int rowi = i0 + wr0 + i * 16 + quad * 4 + r;
        Mo[(size_t)rowi * D_ + col] = f2bf(acc[i][j][r]);
      }
    }
}

// ---------------------------------------------------------------------------
// kPbf64: Ptb[b][v][d] = sum_j Lwb[v,j] * Mb[b][d,j]  (64x64 tiles).
// OUTPUT PRE-SWIZZLED (column-block ^ row&7) for kLogits2's DMA staging.
// ---------------------------------------------------------------------------
__global__ __launch_bounds__(256) void kPbf64(const short* __restrict__ Lwb,
                                              const short* __restrict__ Mb,
                                              short* __restrict__ Ptb) {
  const int b = blockIdx.z;
  const int i0 = blockIdx.x * 64;  // v
  const int j0 = blockIdx.y * 64;  // d
  const short* Bbase = Mb + (size_t)b * D_ * D_;
  __shared__ short As[64 * 64];
  __shared__ short Bs[64 * 64];
  f32x4 acc[2][2] = {};
  const int tid = threadIdx.x;
  const int w = tid >> 6, lane = tid & 63;
  const int quad = lane >> 4, mcol = lane & 15;
  const int wr0 = (w & 1) * 32, wc0 = (w >> 1) * 32;

  for (int k0 = 0; k0 < D_; k0 += 64) {
#pragma unroll
    for (int q = 0; q < 2; ++q) {
      const int u = q * 256 + tid;
      const int row = u >> 3, blk = u & 7;
      const int phys = blk ^ (row & 7);
      *(short8*)(As + row * 64 + phys * 8) =
          *(const short8*)(Lwb + (size_t)(i0 + row) * D_ + k0 + blk * 8);
      *(short8*)(Bs + row * 64 + phys * 8) =
          *(const short8*)(Bbase + (size_t)(j0 + row) * D_ + k0 + blk * 8);
    }
    __syncthreads();
#pragma unroll
    for (int ss = 0; ss < 2; ++ss) {
      short8 af[2], bf[2];
#pragma unroll
      for (int i = 0; i < 2; ++i) {
        const int arow = wr0 + i * 16 + mcol;
        const int ablk = (ss * 4 + quad) ^ (arow & 7);
        af[i] = *(const short8*)(As + arow * 64 + ablk * 8);
        const int brow = wc0 + i * 16 + mcol;
        const int bblk = (ss * 4 + quad) ^ (brow & 7);
        bf[i] = *(const short8*)(Bs + brow * 64 + bblk * 8);
      }
#pragma unroll
      for (int i = 0; i < 2; ++i)
#pragma unroll
        for (int j = 0; j < 2; ++j)
          acc[i][j] = __builtin_amdgcn_mfma_f32_16x16x32_bf16(af[i], bf[j],
                                                              acc[i][j], 0, 0, 0);
    }
    __syncthreads();
  }
  short* Po = Ptb + (size_t)b * VP * D_;
#pragma unroll
  for (int i = 0; i < 2; ++i)
#pragma unroll
    for (int j = 0; j < 2; ++j) {
      const int col = j0 + wc0 + j * 16 + mcol;
#pragma unroll
      for (int r = 0; r < 4; ++r) {
        const int rowi = i0 + wr0 + i * 16 + quad * 4 + r;
        const int key = rowi & 7;
        const int pcol = (col & ~63) | ((((col >> 3) & 7) ^ key) << 3) | (col & 7);
        Po[(size_t)rowi * D_ + pcol] = f2bf(acc[i][j][r]);
      }
    }
}

// ---------------------------------------------------------------------------
// kLogits2: logits[b,l,v] = x[l]·Ptb[v] + c[b,l]*t[b,v] + Lb[v], bf16 out.
// A = Ptb (v-rows), B = xbf (l-rows), both pre-swizzled -> DMA staging.
// GRID: x = l-tile fastest (per-XCD L2 reuse of xbf, round-3/6 validated).
// ---------------------------------------------------------------------------
__global__ __launch_bounds__(256) void kLogits2(const short* __restrict__ xbf,
                                                const short* __restrict__ Ptb,
                                                const float* __restrict__ c,
                                                const float* __restrict__ t,
                                                const float* __restrict__ Lb,
                                                short* __restrict__ logitsBf) {
  const int b = blockIdx.z;
  const int l0t = blockIdx.x * 128;  // l tile (fastest-varying)
  const int v0t = blockIdx.y * 128;  // v tile
  const short* Abase = Ptb + (size_t)b * VP * D_;
  const short* Bbase = xbf + (size_t)b * L_ * D_;
  __shared__ short As[128 * 64];
  __shared__ short Bs[128 * 64];
  f32x4 acc[4][4] = {};
  const int tid = threadIdx.x;
  const int w = tid >> 6, lane = tid & 63;
  const int quad = lane >> 4, mcol = lane & 15;
  const int wr0 = (w & 1) * 64, wc0 = (w >> 1) * 64;

  for (int k0 = 0; k0 < D_; k0 += 64) {
#pragma unroll
    for (int t4 = 0; t4 < 4; ++t4) {
      const int cc = w * 4 + t4;
      const int gr = cc * 8 + (lane >> 3);
      const int gc = k0 + (lane & 7) * 8;
      dma16(Abase + (size_t)(v0t + gr) * D_ + gc, As + cc * 512);
      dma16(Bbase + (size_t)(l0t + gr) * D_ + gc, Bs + cc * 512);
    }
    __syncthreads();
#pragma unroll
    for (int ss = 0; ss < 2; ++ss) {
      short8 af[4], bf[4];
#pragma unroll
      for (int i = 0; i < 4; ++i) {
        const int arow = wr0 + i * 16 + mcol;
        const int ablk = (ss * 4 + quad) ^ (arow & 7);
        af[i] = *(const short8*)(As + arow * 64 + ablk * 8);
        const int brow = wc0 + i * 16 + mcol;
        const int bblk = (ss * 4 + quad) ^ (brow & 7);
        bf[i] = *(const short8*)(Bs + brow * 64 + bblk * 8);
      }
#pragma unroll
      for (int i = 0; i < 4; ++i)
#pragma unroll
        for (int j = 0; j < 4; ++j)
          acc[i][j] = __builtin_amdgcn_mfma_f32_16x16x32_bf16(af[i], bf[j],
                                                              acc[i][j], 0, 0, 0);
    }
    __syncthreads();
  }
  // C[row=v][col=l]: v = v0t+wr0+i*16+quad*4+r (consecutive in r), l = wc0+j*16+mcol
#pragma unroll
  for (int j = 0; j < 4; ++j) {
    const int gl = l0t + wc0 + j * 16 + mcol;
    const float cl = c[b * L_ + gl];
#pragma unroll
    for (int i = 0; i < 4; ++i) {
      const int gv0 = v0t + wr0 + i * 16 + quad * 4;
      f32x4 tv = *(const f32x4*)(t + b * VP + gv0);
      f32x4 lb4 = {};
      if (gv0 < V_) lb4 = *(const f32x4*)(Lb + gv0);  // V_ % 4 == 0
      short4v o;
#pragma unroll
      for (int r = 0; r < 4; ++r)
        o[r] = f2bf(acc[i][j][r] + cl * tv[r] + lb4[r]);
      *(short4v*)(logitsBf + ((size_t)b * L_ + gl) * VP + gv0) = o;
    }
  }
}

// ---------------------------------------------------------------------------
// kLsm: log_softmax over V per (b,l) row, bf16 logits in, fp32 out (L,B,V).
// One wave per row; no LDS, no barriers.
// ---------------------------------------------------------------------------
__global__ __launch_bounds__(256) void kLsm(const short* __restrict__ logitsBf,
                                            float* __restrict__ out) {
  const int b = blockIdx.y;
  const int l = blockIdx.x * 4 + (threadIdx.x >> 6);
  const int lane = threadIdx.x & 63;
  const short* row = logitsBf + ((size_t)b * L_ + l) * VP;
  short8 v0 = *(const short8*)(row + lane * 16);
  short8 v1 = *(const short8*)(row + lane * 16 + 8);
  float vals[16];
#pragma unroll
  for (int i = 0; i < 8; ++i) { vals[i] = bf2f(v0[i]); vals[8 + i] = bf2f(v1[i]); }
  float m = -__builtin_inff();
#pragma unroll
  for (int i = 0; i < 16; ++i)
    if (lane * 16 + i < V_) m = fmaxf(m, vals[i]);
  for (int off = 32; off; off >>= 1) m = fmaxf(m, __shfl_xor(m, off));
  float se = 0.f;
#pragma unroll
  for (int i = 0; i < 16; ++i)
    if (lane * 16 + i < V_) se += expf(vals[i] - m);
  for (int off = 32; off; off >>= 1) se += __shfl_xor(se, off);
  const float lse = m + logf(se);
  float* orow = out + (size_t)l * OUT_BV + b * V_;
#pragma unroll
  for (int q = 0; q < 4; ++q) {
    const int base = lane * 16 + q * 4;
    if (base < V_) {  // V_ % 4 == 0, so base<V_ implies base+3<V_
      float4 st = make_float4(vals[q * 4 + 0] - lse, vals[q * 4 + 1] - lse,
                              vals[q * 4 + 2] - lse, vals[q * 4 + 3] - lse);
      *(float4*)(orow + base) = st;
    }
  }
}

// ---------------------------------------------------------------------------
extern "C" void kernel_launch(void* const* d_in, const int* in_sizes, int n_in,
                              void* d_out, int out_size, void* d_ws,
                              size_t ws_size, hipStream_t stream) {
  const float* x  = (const float*)d_in[0];
  const float* Ww = (const float*)d_in[1];
  const float* Wb = (const float*)d_in[2];
  const float* Lw = (const float*)d_in[3];
  const float* Lb = (const float*)d_in[4];

  char* wp = (char*)d_ws;
  short* xbf = (short*)wp;   wp += (size_t)B_ * L_ * D_ * 2;        // 16 MB
  short* xT  = (short*)wp;   wp += (size_t)B_ * L_ * D_ * 2;        // 16 MB
  short* Ptb = (short*)wp;   wp += (size_t)B_ * VP * D_ * 2;        // 4 MB
  short* Gpart = (short*)wp; wp += (size_t)B_ * NCH * D_ * D_ * 2;  // 32 MB
  short* Gb  = (short*)wp;   wp += (size_t)B_ * D_ * D_ * 2;        // 2 MB
  short* Mb  = (short*)wp;   wp += (size_t)B_ * D_ * D_ * 2;        // 2 MB
  short* Wwb = (short*)wp;   wp += (size_t)D_ * D_ * 2;             // 0.5 MB
  short* Lwb = (short*)wp;   wp += (size_t)VP * D_ * 2;             // 1 MB
  float* s   = (float*)wp;   wp += (size_t)B_ * D_ * 4;             // 8 KB
  float* c   = (float*)wp;   wp += (size_t)B_ * L_ * 4;             // 64 KB
  float* t   = (float*)wp;   wp += (size_t)B_ * VP * 4;             // 16 KB
  short* logitsBf = (short*)wp;                                     // 32 MB

  // zero the atomic accumulators (s and c are contiguous)
  hipMemsetAsync(s, 0, (size_t)(B_ * D_ + B_ * L_) * sizeof(float), stream);

  kPre<<<dim3(64, 8, B_), 256, 0, stream>>>(x, Wb, xbf, xT, s, c);
  kGbf<<<dim3(10, 1, B_ * NCH), 256, 0, stream>>>(xT, Gpart);
  kGredWT<<<dim3(2304), 256, 0, stream>>>(Gpart, Gb, Ww, Lw, Wwb, Lwb, s, t);
  kMbf64<<<dim3(8, 8, B_), 256, 0, stream>>>(Wwb, Gb, Mb);
  kPbf64<<<dim3(16, 8, B_), 256, 0, stream>>>(Lwb, Mb, Ptb);
  kLogits2<<<dim3(32, 8, B_), 256, 0, stream>>>(xbf, Ptb, c, t, Lb, logitsBf);
  kLsm<<<dim3(L_ / 4, B_), 256, 0, stream>>>(logitsBf, (float*)d_out);
}

// Round 8
// 199.318 us; speedup vs baseline: 1.1098x; 1.1098x over previous
//
#include <hip/hip_runtime.h>
#include <math.h>

#define L_ 4096
#define B_ 4
#define D_ 512
#define V_ 1000
#define VP 1024
#define BD 2048     // B_*D_
#define OUT_BV 4000 // B_*V_
#define NCH 8       // split-K chunks for kGbf

typedef __attribute__((ext_vector_type(8))) short short8;
typedef __attribute__((ext_vector_type(4))) float f32x4;
typedef __attribute__((ext_vector_type(4))) short short4v;

typedef __attribute__((address_space(1))) const unsigned int gu32;
typedef __attribute__((address_space(3))) unsigned int lu32;

// async global->LDS DMA, 16 B/lane (wave-level: lands at ldsbase + lane*16)
__device__ __forceinline__ void dma16(const void* g, void* l) {
  __builtin_amdgcn_global_load_lds((gu32*)g, (lu32*)l, 16, 0, 0);
}

__device__ __forceinline__ short f2bf(float f) {
  unsigned u = __float_as_uint(f);
  unsigned r = (u + 0x7FFFu + ((u >> 16) & 1u)) >> 16;
  return (short)r;
}
__device__ __forceinline__ float bf2f(short v) {
  return __uint_as_float(((unsigned)(unsigned short)v) << 16);
}

// ---------------------------------------------------------------------------
// kPre: one pass over x. Produces:
//   xbf (B,L,D) bf16, PRE-SWIZZLED (blk ^= row&7 within 64-elem chunks) for
//     kLogits2's global_load_lds staging;
//   xT (B,D,L) bf16, PLAIN layout (kGbf does swizzle-on-LDS-write);
//   s[b,d]=sum_l x (atomic); c[b,l]=x·Wb (atomic)
// ---------------------------------------------------------------------------
__global__ __launch_bounds__(256) void kPre(const float* __restrict__ x,
                                            const float* __restrict__ Wb,
                                            short* __restrict__ xbf,
                                            short* __restrict__ xT,
                                            float* __restrict__ s,
                                            float* __restrict__ c) {
  const int l0 = blockIdx.x * 64, d0 = blockIdx.y * 64, b = blockIdx.z;
  __shared__ short tile[64 * 72];  // tile[d_local][l_local], stride 72
  const int tid = threadIdx.x;
  const int r = tid >> 2;
  const int q = tid & 3;
  const int c0 = q * 16;
  const int key = r & 7;
  const int blk0 = c0 >> 3;  // 0,2,4,6

  short sv[16];
  float cpart = 0.f;
  const float* src = x + (size_t)(l0 + r) * BD + b * D_ + d0 + c0;
#pragma unroll
  for (int qq = 0; qq < 4; ++qq) {
    float4 f = *(const float4*)(src + qq * 4);
    const float* wb = Wb + d0 + c0 + qq * 4;
    cpart += f.x * wb[0] + f.y * wb[1] + f.z * wb[2] + f.w * wb[3];
    sv[qq * 4 + 0] = f2bf(f.x); sv[qq * 4 + 1] = f2bf(f.y);
    sv[qq * 4 + 2] = f2bf(f.z); sv[qq * 4 + 3] = f2bf(f.w);
  }
  // swizzled xbf store (row = l0+r, chunk base d0)
  short* dst = xbf + ((size_t)b * L_ + l0 + r) * D_ + d0;
  *(short8*)(dst + ((blk0 ^ key) * 8))       = *(short8*)(sv);
  *(short8*)(dst + (((blk0 + 1) ^ key) * 8)) = *(short8*)(sv + 8);
#pragma unroll
  for (int i = 0; i < 16; ++i) tile[(c0 + i) * 72 + r] = sv[i];
  cpart += __shfl_xor(cpart, 1);
  cpart += __shfl_xor(cpart, 2);
  if (q == 0) atomicAdd(&c[b * L_ + l0 + r], cpart);
  __syncthreads();
  short8 t0 = *(const short8*)(tile + r * 72 + c0);
  short8 t1 = *(const short8*)(tile + r * 72 + c0 + 8);
  // plain xT store (row = d0+r, l contiguous)
  short* tdst = xT + ((size_t)b * D_ + d0 + r) * L_ + l0 + c0;
  *(short8*)(tdst)     = t0;
  *(short8*)(tdst + 8) = t1;
  float spart = 0.f;
#pragma unroll
  for (int i = 0; i < 8; ++i) spart += bf2f(t0[i]) + bf2f(t1[i]);
  spart += __shfl_xor(spart, 1);
  spart += __shfl_xor(spart, 2);
  if (q == 0) atomicAdd(&s[b * D_ + d0 + r], spart);
}

// ---------------------------------------------------------------------------
// kGbf: Gpart[z] = xT_b[:,chunk] . xT_b[:,chunk]^T  (bf16 out, 128x128 tiles)
// Round-6-proven version: VGPR staging, swizzle-on-LDS-write, all 16 tiles.
// ---------------------------------------------------------------------------
__global__ __launch_bounds__(256) void kGbf(const short* __restrict__ xT,
                                            short* __restrict__ Gpart) {
  const int z = blockIdx.z;
  const int b = z >> 3, ch = z & 7;
  const int i0 = blockIdx.x * 128, j0 = blockIdx.y * 128;
  const short* Ab = xT + (size_t)b * D_ * L_;
  __shared__ short As[128 * 64];
  __shared__ short Bs[128 * 64];
  f32x4 acc[4][4] = {};
  const int tid = threadIdx.x;
  const int w = tid >> 6, lane = tid & 63;
  const int quad = lane >> 4, mcol = lane & 15;
  const int wr0 = (w & 1) * 64, wc0 = (w >> 1) * 64;
  const int kbase = ch * 512;

  for (int k0 = kbase; k0 < kbase + 512; k0 += 64) {
#pragma unroll
    for (int q = 0; q < 4; ++q) {
      const int u = q * 256 + tid;
      const int row = u >> 3, blk = u & 7;
      const int phys = blk ^ (row & 7);
      *(short8*)(As + row * 64 + phys * 8) =
          *(const short8*)(Ab + (size_t)(i0 + row) * L_ + k0 + blk * 8);
      *(short8*)(Bs + row * 64 + phys * 8) =
          *(const short8*)(Ab + (size_t)(j0 + row) * L_ + k0 + blk * 8);
    }
    __syncthreads();
#pragma unroll
    for (int ss = 0; ss < 2; ++ss) {
      short8 af[4], bf[4];
#pragma unroll
      for (int i = 0; i < 4; ++i) {
        const int arow = wr0 + i * 16 + mcol;
        const int ablk = (ss * 4 + quad) ^ (arow & 7);
        af[i] = *(const short8*)(As + arow * 64 + ablk * 8);
        const int brow = wc0 + i * 16 + mcol;
        const int bblk = (ss * 4 + quad) ^ (brow & 7);
        bf[i] = *(const short8*)(Bs + brow * 64 + bblk * 8);
      }
#pragma unroll
      for (int i = 0; i < 4; ++i)
#pragma unroll
        for (int j = 0; j < 4; ++j)
          acc[i][j] = __builtin_amdgcn_mfma_f32_16x16x32_bf16(af[i], bf[j],
                                                              acc[i][j], 0, 0, 0);
    }
    __syncthreads();
  }
  short* Gp = Gpart + (size_t)z * (D_ * D_);
#pragma unroll
  for (int i = 0; i < 4; ++i)
#pragma unroll
    for (int j = 0; j < 4; ++j) {
      const int col = j0 + wc0 + j * 16 + mcol;
#pragma unroll
      for (int r = 0; r < 4; ++r) {
        const int rowi = i0 + wr0 + i * 16 + quad * 4 + r;
        Gp[(size_t)rowi * D_ + col] = f2bf(acc[i][j][r]);
      }
    }
}

// ---------------------------------------------------------------------------
// kGredWT: blocks [0,512): Gb = sum_ch Gpart.  [512,1280): cast Ww/Lw -> bf16.
// [1280,2304): t[b][v] = dot(Lw[v,:], s[b,:])  (merged kT).
// ---------------------------------------------------------------------------
__global__ __launch_bounds__(256) void kGredWT(const short* __restrict__ Gpart,
                                               short* __restrict__ Gb,
                                               const float* __restrict__ Ww,
                                               const float* __restrict__ Lw,
                                               short* __restrict__ Wwb,
                                               short* __restrict__ Lwb,
                                               const float* __restrict__ s,
                                               float* __restrict__ t) {
  if (blockIdx.x < 512) {
    const int idx = blockIdx.x * 256 + threadIdx.x;  // short8 index
    const int b = idx >> 15, e = (idx & 32767) * 8;
    float sum[8] = {};
#pragma unroll
    for (int ch = 0; ch < NCH; ++ch) {
      short8 v = *(const short8*)(Gpart + ((size_t)(b * NCH + ch)) * (D_ * D_) + e);
#pragma unroll
      for (int i = 0; i < 8; ++i) sum[i] += bf2f(v[i]);
    }
    short8 o;
#pragma unroll
    for (int i = 0; i < 8; ++i) o[i] = f2bf(sum[i]);
    *(short8*)(Gb + (size_t)b * (D_ * D_) + e) = o;
  } else if (blockIdx.x < 1280) {
    const int idx = (blockIdx.x - 512) * 256 + threadIdx.x;  // quad index
    if (idx < 65536) {
      const int e = idx * 4;
      float4 f = *(const float4*)(Ww + e);
      short4v o; o[0] = f2bf(f.x); o[1] = f2bf(f.y); o[2] = f2bf(f.z); o[3] = f2bf(f.w);
      *(short4v*)(Wwb + e) = o;
    } else {
      const int e = (idx - 65536) * 4;
      const int v = e >> 9;
      short4v o = {};
      if (v < V_) {
        float4 f = *(const float4*)(Lw + e);
        o[0] = f2bf(f.x); o[1] = f2bf(f.y); o[2] = f2bf(f.z); o[3] = f2bf(f.w);
      }
      *(short4v*)(Lwb + e) = o;
    }
  } else {
    const int w = threadIdx.x >> 6, lane = threadIdx.x & 63;
    const int wid = (blockIdx.x - 1280) * 4 + w;
    const int b = wid >> 10, v = wid & 1023;
    float sum = 0.f;
    if (v < V_) {
      const float* lr = Lw + (size_t)v * D_;
      const float* sb = s + b * D_;
#pragma unroll
      for (int i = 0; i < 8; ++i) sum += lr[lane + i * 64] * sb[lane + i * 64];
    }
    for (int off = 32; off; off >>= 1) sum += __shfl_down(sum, off);
    if (lane == 0) t[b * VP + v] = (v < V_) ? sum : 0.f;
  }
}

// ---------------------------------------------------------------------------
// kMbf64: Mb[b] = Wwb @ Gb[b]  (64x64 tiles; VGPR staging, unswizzled inputs)
// ---------------------------------------------------------------------------
__global__ __launch_bounds__(256) void kMbf64(const short* __restrict__ Wwb,
                                              const short* __restrict__ Gb,
                                              short* __restrict__ Mb) {
  const int b = blockIdx.z;
  const int i0 = blockIdx.x * 64, j0 = blockIdx.y * 64;
  const short* Bbase = Gb + (size_t)b * D_ * D_;
  __shared__ short As[64 * 64];
  __shared__ short Bs[64 * 64];
  f32x4 acc[2][2] = {};
  const int tid = threadIdx.x;
  const int w = tid >> 6, lane = tid & 63;
  const int quad = lane >> 4, mcol = lane & 15;
  const int wr0 = (w & 1) * 32, wc0 = (w >> 1) * 32;

  for (int k0 = 0; k0 < D_; k0 += 64) {
#pragma unroll
    for (int q = 0; q < 2; ++q) {
      const int u = q * 256 + tid;
      const int row = u >> 3, blk = u & 7;
      const int phys = blk ^ (row & 7);
      *(short8*)(As + row * 64 + phys * 8) =
          *(const short8*)(Wwb + (size_t)(i0 + row) * D_ + k0 + blk * 8);
      *(short8*)(Bs + row * 64 + phys * 8) =
          *(const short8*)(Bbase + (size_t)(j0 + row) * D_ + k0 + blk * 8);
    }
    __syncthreads();
#pragma unroll
    for (int ss = 0; ss < 2; ++ss) {
      short8 af[2], bf[2];
#pragma unroll
      for (int i = 0; i < 2; ++i) {
        const int arow = wr0 + i * 16 + mcol;
        const int ablk = (ss * 4 + quad) ^ (arow & 7);
        af[i] = *(const short8*)(As + arow * 64 + ablk * 8);
        const int brow = wc0 + i * 16 + mcol;
        const int bblk = (ss * 4 + quad) ^ (brow & 7);
        bf[i] = *(const short8*)(Bs + brow * 64 + bblk * 8);
      }
#pragma unroll
      for (int i = 0; i < 2; ++i)
#pragma unroll
        for (int j = 0; j < 2; ++j)
          acc[i][j] = __builtin_amdgcn_mfma_f32_16x16x32_bf16(af[i], bf[j],
                                                              acc[i][j], 0, 0, 0);
    }
    __syncthreads();
  }
  short* Mo = Mb + (size_t)b * D_ * D_;
#pragma unroll
  for (int i = 0; i < 2; ++i)
#pragma unroll
    for (int j = 0; j < 2; ++j) {
      const int col = j0 + wc0 + j * 16 + mcol;
#pragma unroll
      for (int r = 0; r < 4; ++r) {
        const int rowi = i0 + wr0 + i * 16 + quad * 4 + r;
        Mo[(size_t)rowi * D_ + col] = f2bf(acc[i][j][r]);
      }
    }
}

// ---------------------------------------------------------------------------
// kPbf64: Ptb[b][v][d] = sum_j Lwb[v,j] * Mb[b][d,j]  (64x64 tiles).
// OUTPUT PRE-SWIZZLED (column-block ^ row&7) for kLogits2's DMA staging.
// ---------------------------------------------------------------------------
__global__ __launch_bounds__(256) void kPbf64(const short* __restrict__ Lwb,
                                              const short* __restrict__ Mb,
                                              short* __restrict__ Ptb) {
  const int b = blockIdx.z;
  const int i0 = blockIdx.x * 64;  // v
  const int j0 = blockIdx.y * 64;  // d
  const short* Bbase = Mb + (size_t)b * D_ * D_;
  __shared__ short As[64 * 64];
  __shared__ short Bs[64 * 64];
  f32x4 acc[2][2] = {};
  const int tid = threadIdx.x;
  const int w = tid >> 6, lane = tid & 63;
  const int quad = lane >> 4, mcol = lane & 15;
  const int wr0 = (w & 1) * 32, wc0 = (w >> 1) * 32;

  for (int k0 = 0; k0 < D_; k0 += 64) {
#pragma unroll
    for (int q = 0; q < 2; ++q) {
      const int u = q * 256 + tid;
      const int row = u >> 3, blk = u & 7;
      const int phys = blk ^ (row & 7);
      *(short8*)(As + row * 64 + phys * 8) =
          *(const short8*)(Lwb + (size_t)(i0 + row) * D_ + k0 + blk * 8);
      *(short8*)(Bs + row * 64 + phys * 8) =
          *(const short8*)(Bbase + (size_t)(j0 + row) * D_ + k0 + blk * 8);
    }
    __syncthreads();
#pragma unroll
    for (int ss = 0; ss < 2; ++ss) {
      short8 af[2], bf[2];
#pragma unroll
      for (int i = 0; i < 2; ++i) {
        const int arow = wr0 + i * 16 + mcol;
        const int ablk = (ss * 4 + quad) ^ (arow & 7);
        af[i] = *(const short8*)(As + arow * 64 + ablk * 8);
        const int brow = wc0 + i * 16 + mcol;
        const int bblk = (ss * 4 + quad) ^ (brow & 7);
        bf[i] = *(const short8*)(Bs + brow * 64 + bblk * 8);
      }
#pragma unroll
      for (int i = 0; i < 2; ++i)
#pragma unroll
        for (int j = 0; j < 2; ++j)
          acc[i][j] = __builtin_amdgcn_mfma_f32_16x16x32_bf16(af[i], bf[j],
                                                              acc[i][j], 0, 0, 0);
    }
    __syncthreads();
  }
  short* Po = Ptb + (size_t)b * VP * D_;
#pragma unroll
  for (int i = 0; i < 2; ++i)
#pragma unroll
    for (int j = 0; j < 2; ++j) {
      const int col = j0 + wc0 + j * 16 + mcol;
#pragma unroll
      for (int r = 0; r < 4; ++r) {
        const int rowi = i0 + wr0 + i * 16 + quad * 4 + r;
        const int key = rowi & 7;
        const int pcol = (col & ~63) | ((((col >> 3) & 7) ^ key) << 3) | (col & 7);
        Po[(size_t)rowi * D_ + pcol] = f2bf(acc[i][j][r]);
      }
    }
}

// ---------------------------------------------------------------------------
// kLogits2: logits[b,l,v] = x[l]·Ptb[v] + c[b,l]*t[b,v] + Lb[v], bf16 out.
// A = Ptb (v-rows), B = xbf (l-rows), both pre-swizzled -> global_load_lds
// width-16 DMA staging. GRID: x = l-tile fastest (per-XCD L2 reuse of xbf).
// ---------------------------------------------------------------------------
__global__ __launch_bounds__(256) void kLogits2(const short* __restrict__ xbf,
                                                const short* __restrict__ Ptb,
                                                const float* __restrict__ c,
                                                const float* __restrict__ t,
                                                const float* __restrict__ Lb,
                                                short* __restrict__ logitsBf) {
  const int b = blockIdx.z;
  const int l0t = blockIdx.x * 128;  // l tile (fastest-varying)
  const int v0t = blockIdx.y * 128;  // v tile
  const short* Abase = Ptb + (size_t)b * VP * D_;
  const short* Bbase = xbf + (size_t)b * L_ * D_;
  __shared__ short As[128 * 64];
  __shared__ short Bs[128 * 64];
  f32x4 acc[4][4] = {};
  const int tid = threadIdx.x;
  const int w = tid >> 6, lane = tid & 63;
  const int quad = lane >> 4, mcol = lane & 15;
  const int wr0 = (w & 1) * 64, wc0 = (w >> 1) * 64;

  for (int k0 = 0; k0 < D_; k0 += 64) {
#pragma unroll
    for (int t4 = 0; t4 < 4; ++t4) {
      const int cc = w * 4 + t4;
      const int gr = cc * 8 + (lane >> 3);
      const int gc = k0 + (lane & 7) * 8;
      dma16(Abase + (size_t)(v0t + gr) * D_ + gc, As + cc * 512);
      dma16(Bbase + (size_t)(l0t + gr) * D_ + gc, Bs + cc * 512);
    }
    __syncthreads();
#pragma unroll
    for (int ss = 0; ss < 2; ++ss) {
      short8 af[4], bf[4];
#pragma unroll
      for (int i = 0; i < 4; ++i) {
        const int arow = wr0 + i * 16 + mcol;
        const int ablk = (ss * 4 + quad) ^ (arow & 7);
        af[i] = *(const short8*)(As + arow * 64 + ablk * 8);
        const int brow = wc0 + i * 16 + mcol;
        const int bblk = (ss * 4 + quad) ^ (brow & 7);
        bf[i] = *(const short8*)(Bs + brow * 64 + bblk * 8);
      }
#pragma unroll
      for (int i = 0; i < 4; ++i)
#pragma unroll
        for (int j = 0; j < 4; ++j)
          acc[i][j] = __builtin_amdgcn_mfma_f32_16x16x32_bf16(af[i], bf[j],
                                                              acc[i][j], 0, 0, 0);
    }
    __syncthreads();
  }
  // C[row=v][col=l]: v = v0t+wr0+i*16+quad*4+r (consecutive in r), l = wc0+j*16+mcol
#pragma unroll
  for (int j = 0; j < 4; ++j) {
    const int gl = l0t + wc0 + j * 16 + mcol;
    const float cl = c[b * L_ + gl];
#pragma unroll
    for (int i = 0; i < 4; ++i) {
      const int gv0 = v0t + wr0 + i * 16 + quad * 4;
      f32x4 tv = *(const f32x4*)(t + b * VP + gv0);
      f32x4 lb4 = {};
      if (gv0 < V_) lb4 = *(const f32x4*)(Lb + gv0);  // V_ % 4 == 0
      short4v o;
#pragma unroll
      for (int r = 0; r < 4; ++r)
        o[r] = f2bf(acc[i][j][r] + cl * tv[r] + lb4[r]);
      *(short4v*)(logitsBf + ((size_t)b * L_ + gl) * VP + gv0) = o;
    }
  }
}

// ---------------------------------------------------------------------------
// kLsm: log_softmax over V per (b,l) row, bf16 logits in, fp32 out (L,B,V).
// One wave per row; no LDS, no barriers.
// ---------------------------------------------------------------------------
__global__ __launch_bounds__(256) void kLsm(const short* __restrict__ logitsBf,
                                            float* __restrict__ out) {
  const int b = blockIdx.y;
  const int l = blockIdx.x * 4 + (threadIdx.x >> 6);
  const int lane = threadIdx.x & 63;
  const short* row = logitsBf + ((size_t)b * L_ + l) * VP;
  short8 v0 = *(const short8*)(row + lane * 16);
  short8 v1 = *(const short8*)(row + lane * 16 + 8);
  float vals[16];
#pragma unroll
  for (int i = 0; i < 8; ++i) { vals[i] = bf2f(v0[i]); vals[8 + i] = bf2f(v1[i]); }
  float m = -__builtin_inff();
#pragma unroll
  for (int i = 0; i < 16; ++i)
    if (lane * 16 + i < V_) m = fmaxf(m, vals[i]);
  for (int off = 32; off; off >>= 1) m = fmaxf(m, __shfl_xor(m, off));
  float se = 0.f;
#pragma unroll
  for (int i = 0; i < 16; ++i)
    if (lane * 16 + i < V_) se += expf(vals[i] - m);
  for (int off = 32; off; off >>= 1) se += __shfl_xor(se, off);
  const float lse = m + logf(se);
  float* orow = out + (size_t)l * OUT_BV + b * V_;
#pragma unroll
  for (int q = 0; q < 4; ++q) {
    const int base = lane * 16 + q * 4;
    if (base < V_) {  // V_ % 4 == 0, so base<V_ implies base+3<V_
      float4 st = make_float4(vals[q * 4 + 0] - lse, vals[q * 4 + 1] - lse,
                              vals[q * 4 + 2] - lse, vals[q * 4 + 3] - lse);
      *(float4*)(orow + base) = st;
    }
  }
}

// ---------------------------------------------------------------------------
extern "C" void kernel_launch(void* const* d_in, const int* in_sizes, int n_in,
                              void* d_out, int out_size, void* d_ws,
                              size_t ws_size, hipStream_t stream) {
  const float* x  = (const float*)d_in[0];
  const float* Ww = (const float*)d_in[1];
  const float* Wb = (const float*)d_in[2];
  const float* Lw = (const float*)d_in[3];
  const float* Lb = (const float*)d_in[4];

  char* wp = (char*)d_ws;
  short* xbf = (short*)wp;   wp += (size_t)B_ * L_ * D_ * 2;        // 16 MB
  short* xT  = (short*)wp;   wp += (size_t)B_ * L_ * D_ * 2;        // 16 MB
  short* Ptb = (short*)wp;   wp += (size_t)B_ * VP * D_ * 2;        // 4 MB
  short* Gpart = (short*)wp; wp += (size_t)B_ * NCH * D_ * D_ * 2;  // 16 MB
  short* Gb  = (short*)wp;   wp += (size_t)B_ * D_ * D_ * 2;        // 2 MB
  short* Mb  = (short*)wp;   wp += (size_t)B_ * D_ * D_ * 2;        // 2 MB
  short* Wwb = (short*)wp;   wp += (size_t)D_ * D_ * 2;             // 0.5 MB
  short* Lwb = (short*)wp;   wp += (size_t)VP * D_ * 2;             // 1 MB
  float* s   = (float*)wp;   wp += (size_t)B_ * D_ * 4;             // 8 KB
  float* c   = (float*)wp;   wp += (size_t)B_ * L_ * 4;             // 64 KB
  float* t   = (float*)wp;   wp += (size_t)B_ * VP * 4;             // 16 KB
  short* logitsBf = (short*)wp;                                     // 32 MB

  // zero the atomic accumulators (s and c are contiguous)
  hipMemsetAsync(s, 0, (size_t)(B_ * D_ + B_ * L_) * sizeof(float), stream);

  kPre<<<dim3(64, 8, B_), 256, 0, stream>>>(x, Wb, xbf, xT, s, c);
  kGbf<<<dim3(4, 4, B_ * NCH), 256, 0, stream>>>(xT, Gpart);
  kGredWT<<<dim3(2304), 256, 0, stream>>>(Gpart, Gb, Ww, Lw, Wwb, Lwb, s, t);
  kMbf64<<<dim3(8, 8, B_), 256, 0, stream>>>(Wwb, Gb, Mb);
  kPbf64<<<dim3(16, 8, B_), 256, 0, stream>>>(Lwb, Mb, Ptb);
  kLogits2<<<dim3(32, 8, B_), 256, 0, stream>>>(xbf, Ptb, c, t, Lb, logitsBf);
  kLsm<<<dim3(L_ / 4, B_), 256, 0, stream>>>(logitsBf, (float*)d_out);
}